// Round 3
// baseline (697.833 us; speedup 1.0000x reference)
//
#include <hip/hip_runtime.h>

#define C_DIM   256
#define HWN     1024
#define N_TOT   32768
#define NELEM   8388608
#define CHW     (C_DIM*HWN)
#define BIGF    3.4e38f
#define FLAG_CAP 8192
#define MARGIN  0.02f

typedef __attribute__((ext_vector_type(8)))  short bf16x8;
typedef __attribute__((ext_vector_type(16))) float f32x16;

// ---------------- ws layout (floats) ----------------
// idx_arr(int): [0, 32768)
// flag_cnt    : 32768 ; counts_i [32769,33793) ; loss_acc 33793   (memset 4104 B)
// flags(int)  : [33794, 41986)
// enorm       : [41986, 43010)
// csize       : [43010, 44034)
// base(int)   : [44034, 45058)
// offs(int)   : [45058, 46082)
// order(int)  : [46082, 78850)
// ebt(bf16)   : [78852, 340996)     -- 1 MB, fragment-ordered hi/lo codebook
// total ~1.37 MB (round-1-proven ws budget)
//
// zbt (32 MB, fragment-ordered hi/lo z) lives in d_out[0..8388608) == q_out
// region (written later by vq_combine). dw lives in d_out new_emb region.

// ---------------- d_out layout (floats) ----------------
// q_out 0 (8388608) | loss 8388608 | perp 8388609 | token_map 8388610 (32768)
// new_cs 8421378 (1024) | new_ema_w 8422402 (262144) | new_emb 8684546 (262144)

__device__ inline unsigned short bf16_rne(float x) {
    unsigned int u = __float_as_uint(x);
    unsigned int r = (u + 0x7FFF + ((u >> 16) & 1)) >> 16;
    return (unsigned short)r;
}
__device__ inline float bf16_to_f(unsigned short h) {
    return __uint_as_float(((unsigned int)h) << 16);
}

// ---------- codebook prep: e -> fragment-ordered bf16 hi/lo planes ----------
// ebt chunk addressing (ushort units): ((ct*2 + plane)*16 + cs)*512 + lane*8
// fragment mapping: code = ct*32 + (lane&31), c = cs*16 + (lane>>5)*8 + j
__global__ __launch_bounds__(256)
void vq_eprep(const float* __restrict__ e, unsigned short* __restrict__ ebt) {
    const int t = threadIdx.x;
    const int ct = blockIdx.x;          // 0..31
    const int cg = blockIdx.y;          // 0..3 (64-c group)
    const int u = t >> 5;               // 0..7
    const int row = t & 31;             // code within tile
    const float* src = e + (size_t)(ct*32 + row)*C_DIM + cg*64 + u*8;
    const float4 v0 = *(const float4*)(src);
    const float4 v1 = *(const float4*)(src + 4);
    const float xs[8] = {v0.x,v0.y,v0.z,v0.w,v1.x,v1.y,v1.z,v1.w};
    __align__(16) unsigned short hi[8], lo[8];
    #pragma unroll
    for (int j = 0; j < 8; j++) {
        hi[j] = bf16_rne(xs[j]);
        lo[j] = bf16_rne(xs[j] - bf16_to_f(hi[j]));
    }
    const int cs = cg*4 + (u >> 1);
    const int lpos = (u & 1)*32 + row;  // fragment lane
    unsigned short* dhi = ebt + ((size_t)(ct*2 + 0)*16 + cs)*512 + lpos*8;
    unsigned short* dlo = ebt + ((size_t)(ct*2 + 1)*16 + cs)*512 + lpos*8;
    *(uint4*)dhi = *(const uint4*)hi;
    *(uint4*)dlo = *(const uint4*)lo;
}

__global__ void vq_enorm(const float* __restrict__ e, float* __restrict__ enorm) {
    const int t = threadIdx.x;
    const int w = t >> 6;
    const int lane = t & 63;
    const int k = blockIdx.x * 4 + w;
    const float4 v = *(const float4*)(e + (size_t)k * C_DIM + lane * 4);
    float s = fmaf(v.x, v.x, fmaf(v.y, v.y, fmaf(v.z, v.z, v.w * v.w)));
    #pragma unroll
    for (int off = 32; off > 0; off >>= 1) s += __shfl_down(s, off, 64);
    if (lane == 0) enorm[k] = s;
}

// ---------- z prep: z -> fragment-ordered bf16 hi/lo planes (A operand) ----------
// zbt row-tile slab: rt*16384 ushorts; within: (plane*16 + cs)*512 + lane*8
// mapping: n = rt*32 + (lane&31), c = cs*16 + (lane>>5)*8 + j
__global__ __launch_bounds__(256)
void vq_zprep(const float* __restrict__ z, unsigned short* __restrict__ zbt) {
    const int t = threadIdx.x;
    const int rt = blockIdx.x;          // 0..1023
    const int cg = blockIdx.y;          // 0..3
    const int u = t >> 5;
    const int row = t & 31;
    const int n = rt*32 + row;
    const int b = n >> 10, p = n & 1023;
    const float* zb = z + (size_t)b*CHW + p;
    const int c0 = cg*64 + u*8;
    float xs[8];
    #pragma unroll
    for (int j = 0; j < 8; j++) xs[j] = zb[(size_t)(c0 + j)*HWN];
    __align__(16) unsigned short hi[8], lo[8];
    #pragma unroll
    for (int j = 0; j < 8; j++) {
        hi[j] = bf16_rne(xs[j]);
        lo[j] = bf16_rne(xs[j] - bf16_to_f(hi[j]));
    }
    const int cs = cg*4 + (u >> 1);
    const int lpos = (u & 1)*32 + row;
    unsigned short* base = zbt + (size_t)rt*16384;
    *(uint4*)(base + (0*16 + cs)*512 + lpos*8) = *(const uint4*)hi;
    *(uint4*)(base + (16   + cs)*512 + lpos*8) = *(const uint4*)lo;
}

// ---------- MFMA argmin ----------
// 256 blocks x 512 thr. Block: 128 rows, all 1024 codes.
// wave w: row-group rg=w>>1 (32 rows), col-group cg=w&1.
// k-chunk = 64 codes (2 tiles); per wave 1 tile of 32 codes; 16 chunks.
// per chunk: 2 c-phases of 128 c staged in LDS (32 KB slab).
__global__ __launch_bounds__(512, 1)
void vq_argmin_mfma(const unsigned short* __restrict__ zbt,
                    const unsigned short* __restrict__ ebt,
                    const float* __restrict__ enorm,
                    int* __restrict__ idx_arr,
                    int* __restrict__ flag_cnt, int* __restrict__ flags) {
    __shared__ __align__(16) unsigned short eslab[16384];  // 32 KB
    __shared__ float redd[128][2];
    __shared__ float reds[128][2];
    __shared__ int   redi[128][2];

    const int t = threadIdx.x;
    const int lane = t & 63;
    const int w = t >> 6;
    const int rg = w >> 1;
    const int cg = w & 1;
    const int col = lane & 31;
    const int h = lane >> 5;
    const int n0 = blockIdx.x * 128;
    const int rt = (n0 >> 5) + rg;

    // A fragments: 32 rows x 256 c, hi+lo, held in registers (128 VGPR)
    bf16x8 Ahi[16], Alo[16];
    const unsigned short* abase = zbt + (size_t)rt * 16384;
    #pragma unroll
    for (int cs = 0; cs < 16; cs++) {
        Ahi[cs] = *(const bf16x8*)(abase + (0*16 + cs)*512 + lane*8);
        Alo[cs] = *(const bf16x8*)(abase + (16   + cs)*512 + lane*8);
    }

    float bestd[16], secondd[16];
    int   besti[16];
    #pragma unroll
    for (int r = 0; r < 16; r++) { bestd[r] = BIGF; secondd[r] = BIGF; besti[r] = 0x7fffffff; }

    const int piece = t >> 7;                 // staging role: (lt, plane)
    const int tl = t & 127;

    for (int kc = 0; kc < 16; kc++) {
        f32x16 acc = {0,0,0,0,0,0,0,0,0,0,0,0,0,0,0,0};
        #pragma unroll
        for (int ph = 0; ph < 2; ph++) {
            __syncthreads();
            {   // stage 32 KB: pieces (lt=piece>>1, plane=piece&1), 8 cs each
                const int lt = piece >> 1, pl = piece & 1;
                const int ct = kc*2 + lt;
                const unsigned short* src = ebt + ((size_t)(ct*2 + pl)*16 + ph*8)*512 + tl*8;
                unsigned short* dst = eslab + (size_t)piece*4096 + tl*8;
                #pragma unroll
                for (int r = 0; r < 4; r++)
                    *(uint4*)(dst + r*1024) = *(const uint4*)(src + r*1024);
            }
            __syncthreads();
            #pragma unroll
            for (int csl = 0; csl < 8; csl++) {
                const int cs = ph*8 + csl;
                const bf16x8 bh = *(const bf16x8*)(eslab + ((cg*2 + 0)*8 + csl)*512 + lane*8);
                const bf16x8 bl = *(const bf16x8*)(eslab + ((cg*2 + 1)*8 + csl)*512 + lane*8);
                acc = __builtin_amdgcn_mfma_f32_32x32x16_bf16(Ahi[cs], bh, acc, 0, 0, 0);
                acc = __builtin_amdgcn_mfma_f32_32x32x16_bf16(Ahi[cs], bl, acc, 0, 0, 0);
                acc = __builtin_amdgcn_mfma_f32_32x32x16_bf16(Alo[cs], bh, acc, 0, 0, 0);
                acc = __builtin_amdgcn_mfma_f32_32x32x16_bf16(Alo[cs], bl, acc, 0, 0, 0);
            }
        }
        const int code = kc*64 + cg*32 + col;
        const float en = enorm[code];
        #pragma unroll
        for (int r = 0; r < 16; r++) {
            const float d = fmaf(-2.0f, acc[r], en);
            if (d < bestd[r]) { secondd[r] = bestd[r]; bestd[r] = d; besti[r] = code; }
            else if (d < secondd[r]) secondd[r] = d;
        }
    }

    // butterfly argmin+second over the 32 col-lanes (xor masks stay in half)
    #pragma unroll
    for (int m = 1; m < 32; m <<= 1) {
        #pragma unroll
        for (int r = 0; r < 16; r++) {
            const float od = __shfl_xor(bestd[r],   m, 64);
            const int   oi = __shfl_xor(besti[r],   m, 64);
            const float os = __shfl_xor(secondd[r], m, 64);
            const bool take = (od < bestd[r]) || (od == bestd[r] && oi < besti[r]);
            const float ns = take ? fminf(bestd[r], os) : fminf(secondd[r], od);
            if (take) { bestd[r] = od; besti[r] = oi; }
            secondd[r] = ns;
        }
    }
    __syncthreads();
    if (col == 0) {
        #pragma unroll
        for (int r = 0; r < 16; r++) {
            const int row = (r & 3) + 8*(r >> 2) + 4*h;
            redd[rg*32 + row][cg] = bestd[r];
            redi[rg*32 + row][cg] = besti[r];
            reds[rg*32 + row][cg] = secondd[r];
        }
    }
    __syncthreads();
    if (t < 128) {
        const float d0 = redd[t][0], d1 = redd[t][1];
        const int   i0 = redi[t][0], i1 = redi[t][1];
        const float s0 = reds[t][0], s1 = reds[t][1];
        const bool take = (d1 < d0) || (d1 == d0 && i1 < i0);
        const float bd = take ? d1 : d0;
        const int   bi = take ? i1 : i0;
        const float sd = take ? fminf(d0, s1) : fminf(s0, d1);
        const int n = n0 + t;
        idx_arr[n] = bi;
        if (sd - bd < MARGIN) {
            const int pos = atomicAdd(flag_cnt, 1);
            if (pos < FLAG_CAP) flags[pos] = n;
        }
    }
}

// ---------- exact fp32 re-argmin for near-tie points ----------
__global__ __launch_bounds__(256)
void vq_fix(const float* __restrict__ z, const float* __restrict__ e,
            const float* __restrict__ enorm,
            const int* __restrict__ flag_cnt, const int* __restrict__ flags,
            int* __restrict__ idx_arr) {
    __shared__ float zrow[256];
    __shared__ float rd[256];
    __shared__ int   ri[256];
    const int t = threadIdx.x;
    int cnt = *flag_cnt;
    if (cnt > FLAG_CAP) cnt = FLAG_CAP;
    for (int fi = blockIdx.x; fi < cnt; fi += (int)gridDim.x) {
        const int n = flags[fi];
        const int b = n >> 10, p = n & 1023;
        __syncthreads();
        zrow[t] = z[(size_t)b*CHW + (size_t)t*HWN + p];
        __syncthreads();
        float bd = BIGF; int bi = 0;
        for (int q = 0; q < 4; q++) {
            const int k = t*4 + q;
            const float* er = e + (size_t)k*C_DIM;
            float acc = 0.0f;
            for (int c = 0; c < C_DIM; c += 4) {
                const float4 ev = *(const float4*)(er + c);
                acc = fmaf(ev.x, zrow[c],   acc);
                acc = fmaf(ev.y, zrow[c+1], acc);
                acc = fmaf(ev.z, zrow[c+2], acc);
                acc = fmaf(ev.w, zrow[c+3], acc);
            }
            const float d = fmaf(-2.0f, acc, enorm[k]);
            if (d < bd) { bd = d; bi = k; }       // q ascending -> lowest k on tie
        }
        rd[t] = bd; ri[t] = bi;
        __syncthreads();
        for (int s = 128; s > 0; s >>= 1) {
            if (t < s) {
                const float d2 = rd[t+s]; const int i2 = ri[t+s];
                if (d2 < rd[t] || (d2 == rd[t] && i2 < ri[t])) { rd[t] = d2; ri[t] = i2; }
            }
            __syncthreads();
        }
        if (t == 0) idx_arr[n] = ri[0];
    }
}

__global__ __launch_bounds__(256)
void vq_count(const int* __restrict__ idx_arr, int* __restrict__ counts_i) {
    const int n = blockIdx.x * 256 + threadIdx.x;
    atomicAdd(&counts_i[idx_arr[n]], 1);
}

// 1 block, 1024 threads: EMA cluster size, csize, perplexity, prefix scan.
__global__ void vq_scan_small(const int* __restrict__ counts_i,
                              const float* __restrict__ ema_cs,
                              float* __restrict__ out_perp,
                              float* __restrict__ out_ncs,
                              float* __restrict__ csize,
                              int* __restrict__ base, int* __restrict__ offs) {
    __shared__ float sf[1024];
    __shared__ int si[1024];
    const int t = threadIdx.x;
    const int ci = counts_i[t];
    const float cnt = (float)ci;
    const float ncs = ema_cs[t] * 0.99f + 0.01f * cnt;
    out_ncs[t] = ncs;

    sf[t] = ncs;
    __syncthreads();
    for (int s = 512; s > 0; s >>= 1) { if (t < s) sf[t] += sf[t + s]; __syncthreads(); }
    const float n_total = sf[0];
    __syncthreads();

    csize[t] = (ncs + 1e-10f) / (n_total + 1024.0f * 1e-10f) * n_total;

    const float pr = cnt * (1.0f / 32768.0f);
    sf[t] = pr * logf(pr + 1e-10f);
    __syncthreads();
    for (int s = 512; s > 0; s >>= 1) { if (t < s) sf[t] += sf[t + s]; __syncthreads(); }
    if (t == 0) out_perp[0] = expf(-sf[0]);

    si[t] = ci;
    __syncthreads();
    for (int d = 1; d < 1024; d <<= 1) {
        const int x = si[t];
        const int y = (t >= d) ? si[t - d] : 0;
        __syncthreads();
        si[t] = x + y;
        __syncthreads();
    }
    const int excl = si[t] - ci;
    base[t] = excl;
    offs[t] = excl;
}

__global__ __launch_bounds__(256)
void vq_scatter(const int* __restrict__ idx_arr, int* __restrict__ offs,
                int* __restrict__ order) {
    const int n = blockIdx.x * 256 + threadIdx.x;
    const int idx = idx_arr[n];
    const int pos = atomicAdd(&offs[idx], 1);
    order[pos] = n;
}

// dw[k][c] from bf16 hi/lo planes (hi+lo ~ fp32 to 1e-5 rel). No atomics.
__global__ __launch_bounds__(256)
void vq_dw(const unsigned short* __restrict__ zbt, const int* __restrict__ order,
           const int* __restrict__ base, const int* __restrict__ counts_i,
           float* __restrict__ dw) {
    const int k = blockIdx.x;
    const int t = threadIdx.x;          // channel c
    const int cs = t >> 4;
    const int hh = (t >> 3) & 1;
    const int j = t & 7;
    const int start = base[k];
    const int cnt = counts_i[k];
    float acc = 0.0f;
    for (int i = 0; i < cnt; i++) {
        const int n = order[start + i];
        const int rt = n >> 5, row = n & 31;
        const unsigned short* pb = zbt + (size_t)rt*16384 + (size_t)cs*512 + (hh*32 + row)*8 + j;
        acc += bf16_to_f(pb[0]) + bf16_to_f(pb[8192]);
    }
    dw[(size_t)k*C_DIM + t] = acc;
}

// q_out, token_map, loss. Runs AFTER vq_dw (overwrites zbt region with q).
__global__ __launch_bounds__(256)
void vq_combine(const float* __restrict__ z, const float* __restrict__ e,
                const int* __restrict__ idx_arr,
                float* __restrict__ loss_acc,
                float* __restrict__ qout, float* __restrict__ tokmap) {
    const int t = threadIdx.x;
    const int n = blockIdx.x * 256 + t;
    const int csplit = blockIdx.y;
    const int b = n >> 10, p = n & 1023;
    const int idx = idx_arr[n];
    if (csplit == 0) tokmap[n] = (float)idx;

    const float* zrow = z + (size_t)b*CHW + p;
    float* qrow = qout + (size_t)b*CHW + p;
    const float* erow = e + (size_t)idx*C_DIM;

    float lsum = 0.0f;
    for (int cc = 0; cc < 64; cc += 16) {
        const int cb = csplit*64 + cc;
        float ev[16];
        #pragma unroll
        for (int q4 = 0; q4 < 4; q4++) {
            const float4 v = *(const float4*)(erow + cb + q4*4);
            ev[q4*4+0] = v.x; ev[q4*4+1] = v.y; ev[q4*4+2] = v.z; ev[q4*4+3] = v.w;
        }
        #pragma unroll
        for (int j = 0; j < 16; j++) {
            const float zv = zrow[(size_t)(cb + j) * HWN];
            qrow[(size_t)(cb + j) * HWN] = ev[j];
            const float df = ev[j] - zv;
            lsum = fmaf(df, df, lsum);
        }
    }
    #pragma unroll
    for (int off = 32; off > 0; off >>= 1) lsum += __shfl_down(lsum, off, 64);
    __shared__ float ls[4];
    if ((t & 63) == 0) ls[t >> 6] = lsum;
    __syncthreads();
    if (t == 0) atomicAdd(loss_acc, ls[0] + ls[1] + ls[2] + ls[3]);
}

// new_ema_w, new_embedding, loss. dw aliases out_emb (read-before-write per elem).
__global__ __launch_bounds__(256)
void vq_finalize_big(const float* __restrict__ ema_w, const float* __restrict__ dw,
                     const float* __restrict__ csize, const float* __restrict__ loss_acc,
                     float* __restrict__ out_ema_w, float* __restrict__ out_emb,
                     float* __restrict__ out_loss) {
    const int i4 = blockIdx.x * 256 + threadIdx.x;
    const int k = i4 >> 6;
    const float4 w = ((const float4*)ema_w)[i4];
    const float4 d = ((const float4*)dw)[i4];
    float4 nw;
    nw.x = fmaf(w.x, 0.99f, 0.01f * d.x);
    nw.y = fmaf(w.y, 0.99f, 0.01f * d.y);
    nw.z = fmaf(w.z, 0.99f, 0.01f * d.z);
    nw.w = fmaf(w.w, 0.99f, 0.01f * d.w);
    ((float4*)out_ema_w)[i4] = nw;
    const float cs = csize[k];
    float4 ne;
    ne.x = nw.x / cs; ne.y = nw.y / cs; ne.z = nw.z / cs; ne.w = nw.w / cs;
    ((float4*)out_emb)[i4] = ne;
    if (i4 == 0) out_loss[0] = 0.25f * loss_acc[0] * (1.0f / (float)NELEM);
}

extern "C" void kernel_launch(void* const* d_in, const int* in_sizes, int n_in,
                              void* d_out, int out_size, void* d_ws, size_t ws_size,
                              hipStream_t stream) {
    const float* z      = (const float*)d_in[0];
    const float* e      = (const float*)d_in[1];
    const float* ema_cs = (const float*)d_in[2];
    const float* ema_w  = (const float*)d_in[3];
    float* out = (float*)d_out;
    float* ws  = (float*)d_ws;

    int*   idx_arr  = (int*)ws;
    int*   flag_cnt = (int*)(ws + 32768);
    int*   counts_i = (int*)(ws + 32769);
    float* loss_acc = ws + 33793;
    int*   flags    = (int*)(ws + 33794);
    float* enorm    = ws + 41986;
    float* csize    = ws + 43010;
    int*   base     = (int*)(ws + 44034);
    int*   offs     = (int*)(ws + 45058);
    int*   order    = (int*)(ws + 46082);
    unsigned short* ebt = (unsigned short*)(ws + 78852);

    unsigned short* zbt = (unsigned short*)out;     // q_out region, written later
    float* dw = out + 8684546;                      // new_emb region (aliased)

    // zero flag_cnt + counts_i + loss_acc (contiguous 1026 words)
    hipMemsetAsync(ws + 32768, 0, 4104, stream);

    vq_eprep<<<dim3(32, 4), 256, 0, stream>>>(e, ebt);
    vq_enorm<<<256, 256, 0, stream>>>(e, enorm);
    vq_zprep<<<dim3(1024, 4), 256, 0, stream>>>(z, zbt);
    vq_argmin_mfma<<<256, 512, 0, stream>>>(zbt, ebt, enorm, idx_arr, flag_cnt, flags);
    vq_fix<<<64, 256, 0, stream>>>(z, e, enorm, flag_cnt, flags, idx_arr);
    vq_count<<<128, 256, 0, stream>>>(idx_arr, counts_i);
    vq_scan_small<<<1, 1024, 0, stream>>>(counts_i, ema_cs,
                                          out + 8388609, out + 8421378, csize, base, offs);
    vq_scatter<<<128, 256, 0, stream>>>(idx_arr, offs, order);
    vq_dw<<<1024, 256, 0, stream>>>(zbt, order, base, counts_i, dw);
    vq_combine<<<dim3(128, 4), 256, 0, stream>>>(z, e, idx_arr, loss_acc,
                                                 out, out + 8388610);
    vq_finalize_big<<<256, 256, 0, stream>>>(ema_w, dw, csize, loss_acc,
                                             out + 8422402, out + 8684546,
                                             out + 8388608);
}

// Round 4
// 415.638 us; speedup vs baseline: 1.6789x; 1.6789x over previous
//
#include <hip/hip_runtime.h>

#define C_DIM   256
#define HWN     1024
#define N_TOT   32768
#define NELEM   8388608
#define CHW     (C_DIM*HWN)
#define BIGF    3.4e38f
#define FLAG_CAP 8192
#define MARGIN  0.02f

typedef __attribute__((ext_vector_type(8)))  short bf16x8;
typedef __attribute__((ext_vector_type(16))) float f32x16;

// ---------------- ws layout (floats) ----------------
// idx_arr(int): [0, 32768)
// flag_cnt    : 32768 ; counts_i [32769,33793) ; loss_acc 33793   (memset 4104 B)
// flags(int)  : [33794, 41986)
// enorm       : [41986, 43010)
// csize       : [43010, 44034)
// base(int)   : [44034, 45058)
// offs(int)   : [45058, 46082)
// order(int)  : [46082, 78850)
// ebt(bf16)   : [78852, 340996)     -- 1 MB, fragment-ordered hi/lo codebook
// total ~1.37 MB (proven ws budget)
//
// zbt (33.5 MB, fragment-ordered hi/lo z) lives in d_out q_out region
// (q written later by vq_combine). dw lives in d_out new_emb region.

__device__ inline unsigned short bf16_rne(float x) {
    unsigned int u = __float_as_uint(x);
    unsigned int r = (u + 0x7FFF + ((u >> 16) & 1)) >> 16;
    return (unsigned short)r;
}
__device__ inline float bf16_to_f(unsigned short h) {
    return __uint_as_float(((unsigned int)h) << 16);
}

// ---------- codebook prep: e -> fragment-ordered bf16 hi/lo planes ----------
__global__ __launch_bounds__(256)
void vq_eprep(const float* __restrict__ e, unsigned short* __restrict__ ebt) {
    const int t = threadIdx.x;
    const int ct = blockIdx.x;          // 0..31
    const int cg = blockIdx.y;          // 0..3
    const int u = t >> 5;
    const int row = t & 31;
    const float* src = e + (size_t)(ct*32 + row)*C_DIM + cg*64 + u*8;
    const float4 v0 = *(const float4*)(src);
    const float4 v1 = *(const float4*)(src + 4);
    const float xs[8] = {v0.x,v0.y,v0.z,v0.w,v1.x,v1.y,v1.z,v1.w};
    __align__(16) unsigned short hi[8], lo[8];
    #pragma unroll
    for (int j = 0; j < 8; j++) {
        hi[j] = bf16_rne(xs[j]);
        lo[j] = bf16_rne(xs[j] - bf16_to_f(hi[j]));
    }
    const int cs = cg*4 + (u >> 1);
    const int lpos = (u & 1)*32 + row;
    unsigned short* dhi = ebt + ((size_t)(ct*2 + 0)*16 + cs)*512 + lpos*8;
    unsigned short* dlo = ebt + ((size_t)(ct*2 + 1)*16 + cs)*512 + lpos*8;
    *(uint4*)dhi = *(const uint4*)hi;
    *(uint4*)dlo = *(const uint4*)lo;
}

__global__ void vq_enorm(const float* __restrict__ e, float* __restrict__ enorm) {
    const int t = threadIdx.x;
    const int w = t >> 6;
    const int lane = t & 63;
    const int k = blockIdx.x * 4 + w;
    const float4 v = *(const float4*)(e + (size_t)k * C_DIM + lane * 4);
    float s = fmaf(v.x, v.x, fmaf(v.y, v.y, fmaf(v.z, v.z, v.w * v.w)));
    #pragma unroll
    for (int off = 32; off > 0; off >>= 1) s += __shfl_down(s, off, 64);
    if (lane == 0) enorm[k] = s;
}

// ---------- z prep ----------
__global__ __launch_bounds__(256)
void vq_zprep(const float* __restrict__ z, unsigned short* __restrict__ zbt) {
    const int t = threadIdx.x;
    const int rt = blockIdx.x;
    const int cg = blockIdx.y;
    const int u = t >> 5;
    const int row = t & 31;
    const int n = rt*32 + row;
    const int b = n >> 10, p = n & 1023;
    const float* zb = z + (size_t)b*CHW + p;
    const int c0 = cg*64 + u*8;
    float xs[8];
    #pragma unroll
    for (int j = 0; j < 8; j++) xs[j] = zb[(size_t)(c0 + j)*HWN];
    __align__(16) unsigned short hi[8], lo[8];
    #pragma unroll
    for (int j = 0; j < 8; j++) {
        hi[j] = bf16_rne(xs[j]);
        lo[j] = bf16_rne(xs[j] - bf16_to_f(hi[j]));
    }
    const int cs = cg*4 + (u >> 1);
    const int lpos = (u & 1)*32 + row;
    unsigned short* base = zbt + (size_t)rt*16384;
    *(uint4*)(base + (0*16 + cs)*512 + lpos*8) = *(const uint4*)hi;
    *(uint4*)(base + (16   + cs)*512 + lpos*8) = *(const uint4*)lo;
}

// ---------- MFMA argmin (counts fused into final writer) ----------
__global__ __launch_bounds__(512, 1)
void vq_argmin_mfma(const unsigned short* __restrict__ zbt,
                    const unsigned short* __restrict__ ebt,
                    const float* __restrict__ enorm,
                    int* __restrict__ idx_arr, int* __restrict__ counts_i,
                    int* __restrict__ flag_cnt, int* __restrict__ flags) {
    __shared__ __align__(16) unsigned short eslab[16384];
    __shared__ float redd[128][2];
    __shared__ float reds[128][2];
    __shared__ int   redi[128][2];

    const int t = threadIdx.x;
    const int lane = t & 63;
    const int w = t >> 6;
    const int rg = w >> 1;
    const int cg = w & 1;
    const int col = lane & 31;
    const int h = lane >> 5;
    const int n0 = blockIdx.x * 128;
    const int rt = (n0 >> 5) + rg;

    bf16x8 Ahi[16], Alo[16];
    const unsigned short* abase = zbt + (size_t)rt * 16384;
    #pragma unroll
    for (int cs = 0; cs < 16; cs++) {
        Ahi[cs] = *(const bf16x8*)(abase + (0*16 + cs)*512 + lane*8);
        Alo[cs] = *(const bf16x8*)(abase + (16   + cs)*512 + lane*8);
    }

    float bestd[16], secondd[16];
    int   besti[16];
    #pragma unroll
    for (int r = 0; r < 16; r++) { bestd[r] = BIGF; secondd[r] = BIGF; besti[r] = 0x7fffffff; }

    const int piece = t >> 7;
    const int tl = t & 127;

    for (int kc = 0; kc < 16; kc++) {
        f32x16 acc = {0,0,0,0,0,0,0,0,0,0,0,0,0,0,0,0};
        #pragma unroll
        for (int ph = 0; ph < 2; ph++) {
            __syncthreads();
            {
                const int lt = piece >> 1, pl = piece & 1;
                const int ct = kc*2 + lt;
                const unsigned short* src = ebt + ((size_t)(ct*2 + pl)*16 + ph*8)*512 + tl*8;
                unsigned short* dst = eslab + (size_t)piece*4096 + tl*8;
                #pragma unroll
                for (int r = 0; r < 4; r++)
                    *(uint4*)(dst + r*1024) = *(const uint4*)(src + r*1024);
            }
            __syncthreads();
            #pragma unroll
            for (int csl = 0; csl < 8; csl++) {
                const int cs = ph*8 + csl;
                const bf16x8 bh = *(const bf16x8*)(eslab + ((cg*2 + 0)*8 + csl)*512 + lane*8);
                const bf16x8 bl = *(const bf16x8*)(eslab + ((cg*2 + 1)*8 + csl)*512 + lane*8);
                acc = __builtin_amdgcn_mfma_f32_32x32x16_bf16(Ahi[cs], bh, acc, 0, 0, 0);
                acc = __builtin_amdgcn_mfma_f32_32x32x16_bf16(Ahi[cs], bl, acc, 0, 0, 0);
                acc = __builtin_amdgcn_mfma_f32_32x32x16_bf16(Alo[cs], bh, acc, 0, 0, 0);
                acc = __builtin_amdgcn_mfma_f32_32x32x16_bf16(Alo[cs], bl, acc, 0, 0, 0);
            }
        }
        const int code = kc*64 + cg*32 + col;
        const float en = enorm[code];
        #pragma unroll
        for (int r = 0; r < 16; r++) {
            const float d = fmaf(-2.0f, acc[r], en);
            if (d < bestd[r]) { secondd[r] = bestd[r]; bestd[r] = d; besti[r] = code; }
            else if (d < secondd[r]) secondd[r] = d;
        }
    }

    #pragma unroll
    for (int m = 1; m < 32; m <<= 1) {
        #pragma unroll
        for (int r = 0; r < 16; r++) {
            const float od = __shfl_xor(bestd[r],   m, 64);
            const int   oi = __shfl_xor(besti[r],   m, 64);
            const float os = __shfl_xor(secondd[r], m, 64);
            const bool take = (od < bestd[r]) || (od == bestd[r] && oi < besti[r]);
            const float ns = take ? fminf(bestd[r], os) : fminf(secondd[r], od);
            if (take) { bestd[r] = od; besti[r] = oi; }
            secondd[r] = ns;
        }
    }
    __syncthreads();
    if (col == 0) {
        #pragma unroll
        for (int r = 0; r < 16; r++) {
            const int row = (r & 3) + 8*(r >> 2) + 4*h;
            redd[rg*32 + row][cg] = bestd[r];
            redi[rg*32 + row][cg] = besti[r];
            reds[rg*32 + row][cg] = secondd[r];
        }
    }
    __syncthreads();
    if (t < 128) {
        const float d0 = redd[t][0], d1 = redd[t][1];
        const int   i0 = redi[t][0], i1 = redi[t][1];
        const float s0 = reds[t][0], s1 = reds[t][1];
        const bool take = (d1 < d0) || (d1 == d0 && i1 < i0);
        const float bd = take ? d1 : d0;
        const int   bi = take ? i1 : i0;
        const float sd = take ? fminf(d0, s1) : fminf(s0, d1);
        const int n = n0 + t;
        idx_arr[n] = bi;
        atomicAdd(&counts_i[bi], 1);
        if (sd - bd < MARGIN) {
            const int pos = atomicAdd(flag_cnt, 1);
            if (pos < FLAG_CAP) flags[pos] = n;
        }
    }
}

// ---------- exact fp32 re-argmin for near-tie points (fixes counts too) ----------
__global__ __launch_bounds__(256)
void vq_fix(const float* __restrict__ z, const float* __restrict__ e,
            const float* __restrict__ enorm,
            const int* __restrict__ flag_cnt, const int* __restrict__ flags,
            int* __restrict__ idx_arr, int* __restrict__ counts_i) {
    __shared__ float zrow[256];
    __shared__ float rd[256];
    __shared__ int   ri[256];
    const int t = threadIdx.x;
    int cnt = *flag_cnt;
    if (cnt > FLAG_CAP) cnt = FLAG_CAP;
    for (int fi = blockIdx.x; fi < cnt; fi += (int)gridDim.x) {
        const int n = flags[fi];
        const int b = n >> 10, p = n & 1023;
        __syncthreads();
        zrow[t] = z[(size_t)b*CHW + (size_t)t*HWN + p];
        __syncthreads();
        float bd = BIGF; int bi = 0;
        for (int q = 0; q < 4; q++) {
            const int k = t*4 + q;
            const float* er = e + (size_t)k*C_DIM;
            float acc = 0.0f;
            for (int c = 0; c < C_DIM; c += 4) {
                const float4 ev = *(const float4*)(er + c);
                acc = fmaf(ev.x, zrow[c],   acc);
                acc = fmaf(ev.y, zrow[c+1], acc);
                acc = fmaf(ev.z, zrow[c+2], acc);
                acc = fmaf(ev.w, zrow[c+3], acc);
            }
            const float d = fmaf(-2.0f, acc, enorm[k]);
            if (d < bd) { bd = d; bi = k; }
        }
        rd[t] = bd; ri[t] = bi;
        __syncthreads();
        for (int s = 128; s > 0; s >>= 1) {
            if (t < s) {
                const float d2 = rd[t+s]; const int i2 = ri[t+s];
                if (d2 < rd[t] || (d2 == rd[t] && i2 < ri[t])) { rd[t] = d2; ri[t] = i2; }
            }
            __syncthreads();
        }
        if (t == 0) {
            const int old = idx_arr[n];
            if (ri[0] != old) {
                idx_arr[n] = ri[0];
                atomicAdd(&counts_i[old], -1);
                atomicAdd(&counts_i[ri[0]], 1);
            }
        }
        __syncthreads();
    }
}

// 1 block, 1024 threads: EMA cluster size, csize, perplexity, prefix scan.
__global__ void vq_scan_small(const int* __restrict__ counts_i,
                              const float* __restrict__ ema_cs,
                              float* __restrict__ out_perp,
                              float* __restrict__ out_ncs,
                              float* __restrict__ csize,
                              int* __restrict__ base, int* __restrict__ offs) {
    __shared__ float sf[1024];
    __shared__ int si[1024];
    const int t = threadIdx.x;
    const int ci = counts_i[t];
    const float cnt = (float)ci;
    const float ncs = ema_cs[t] * 0.99f + 0.01f * cnt;
    out_ncs[t] = ncs;

    sf[t] = ncs;
    __syncthreads();
    for (int s = 512; s > 0; s >>= 1) { if (t < s) sf[t] += sf[t + s]; __syncthreads(); }
    const float n_total = sf[0];
    __syncthreads();

    csize[t] = (ncs + 1e-10f) / (n_total + 1024.0f * 1e-10f) * n_total;

    const float pr = cnt * (1.0f / 32768.0f);
    sf[t] = pr * logf(pr + 1e-10f);
    __syncthreads();
    for (int s = 512; s > 0; s >>= 1) { if (t < s) sf[t] += sf[t + s]; __syncthreads(); }
    if (t == 0) out_perp[0] = expf(-sf[0]);

    si[t] = ci;
    __syncthreads();
    for (int d = 1; d < 1024; d <<= 1) {
        const int x = si[t];
        const int y = (t >= d) ? si[t - d] : 0;
        __syncthreads();
        si[t] = x + y;
        __syncthreads();
    }
    const int excl = si[t] - ci;
    base[t] = excl;
    offs[t] = excl;
}

__global__ __launch_bounds__(256)
void vq_scatter(const int* __restrict__ idx_arr, int* __restrict__ offs,
                int* __restrict__ order) {
    const int n = blockIdx.x * 256 + threadIdx.x;
    const int idx = idx_arr[n];
    const int pos = atomicAdd(&offs[idx], 1);
    order[pos] = n;
}

// ---------- dw v2: wave-per-point coalesced reads, unroll-8, LDS reduce ----------
// lane l: plane=l>>5, cs=(l>>1)&15, hh=l&1 -> 8 channels c = cs*16+hh*8+j.
// One wave instruction reads a whole point's 1 KB (hi+lo).
__global__ __launch_bounds__(256)
void vq_dw(const unsigned short* __restrict__ zbt, const int* __restrict__ order,
           const int* __restrict__ base, const int* __restrict__ counts_i,
           float* __restrict__ dw) {
    __shared__ int sord[1024];
    __shared__ float red[4][256];
    const int k = blockIdx.x;
    const int t = threadIdx.x;
    const int w = t >> 6;
    const int l = t & 63;
    const int plane = l >> 5;
    const int cs = (l >> 1) & 15;
    const int hh = l & 1;
    const int start = base[k];
    const int cnt = counts_i[k];
    const size_t loff = (size_t)(plane*16 + cs)*512 + hh*256;

    float acc[8] = {0,0,0,0,0,0,0,0};

    for (int s0 = 0; s0 < cnt; s0 += 1024) {
        const int m = min(1024, cnt - s0);
        __syncthreads();
        for (int i = t; i < m; i += 256) sord[i] = order[start + s0 + i];
        __syncthreads();
        const int mm = m & ~31;
        for (int g0 = w*8; g0 < mm; g0 += 32) {
            uint4 v[8];
            #pragma unroll
            for (int r = 0; r < 8; r++) {
                const int n = sord[g0 + r];
                const int rt = n >> 5, row = n & 31;
                v[r] = *(const uint4*)(zbt + (size_t)rt*16384 + loff + row*8);
            }
            #pragma unroll
            for (int r = 0; r < 8; r++) {
                const unsigned short* u = (const unsigned short*)&v[r];
                #pragma unroll
                for (int j = 0; j < 8; j++) acc[j] += bf16_to_f(u[j]);
            }
        }
        for (int i = mm + w; i < m; i += 4) {
            const int n = sord[i];
            const int rt = n >> 5, row = n & 31;
            const uint4 v = *(const uint4*)(zbt + (size_t)rt*16384 + loff + row*8);
            const unsigned short* u = (const unsigned short*)&v;
            #pragma unroll
            for (int j = 0; j < 8; j++) acc[j] += bf16_to_f(u[j]);
        }
    }

    // combine hi(plane0)+lo(plane1): lanes l and l^32 share (cs,hh)
    #pragma unroll
    for (int j = 0; j < 8; j++) acc[j] += __shfl_xor(acc[j], 32, 64);
    if (l < 32) {
        #pragma unroll
        for (int j = 0; j < 8; j++) red[w][cs*16 + hh*8 + j] = acc[j];
    }
    __syncthreads();
    dw[(size_t)k*C_DIM + t] = red[0][t] + red[1][t] + red[2][t] + red[3][t];
}

// q_out, token_map, loss. Runs AFTER vq_dw (overwrites zbt region with q).
__global__ __launch_bounds__(256)
void vq_combine(const float* __restrict__ z, const float* __restrict__ e,
                const int* __restrict__ idx_arr,
                float* __restrict__ loss_acc,
                float* __restrict__ qout, float* __restrict__ tokmap) {
    const int t = threadIdx.x;
    const int n = blockIdx.x * 256 + t;
    const int csplit = blockIdx.y;
    const int b = n >> 10, p = n & 1023;
    const int idx = idx_arr[n];
    if (csplit == 0) tokmap[n] = (float)idx;

    const float* zrow = z + (size_t)b*CHW + p;
    float* qrow = qout + (size_t)b*CHW + p;
    const float* erow = e + (size_t)idx*C_DIM;

    float lsum = 0.0f;
    for (int cc = 0; cc < 64; cc += 16) {
        const int cb = csplit*64 + cc;
        float ev[16];
        #pragma unroll
        for (int q4 = 0; q4 < 4; q4++) {
            const float4 v = *(const float4*)(erow + cb + q4*4);
            ev[q4*4+0] = v.x; ev[q4*4+1] = v.y; ev[q4*4+2] = v.z; ev[q4*4+3] = v.w;
        }
        #pragma unroll
        for (int j = 0; j < 16; j++) {
            const float zv = zrow[(size_t)(cb + j) * HWN];
            qrow[(size_t)(cb + j) * HWN] = ev[j];
            const float df = ev[j] - zv;
            lsum = fmaf(df, df, lsum);
        }
    }
    #pragma unroll
    for (int off = 32; off > 0; off >>= 1) lsum += __shfl_down(lsum, off, 64);
    __shared__ float ls[4];
    if ((t & 63) == 0) ls[t >> 6] = lsum;
    __syncthreads();
    if (t == 0) atomicAdd(loss_acc, ls[0] + ls[1] + ls[2] + ls[3]);
}

__global__ __launch_bounds__(256)
void vq_finalize_big(const float* __restrict__ ema_w, const float* __restrict__ dw,
                     const float* __restrict__ csize, const float* __restrict__ loss_acc,
                     float* __restrict__ out_ema_w, float* __restrict__ out_emb,
                     float* __restrict__ out_loss) {
    const int i4 = blockIdx.x * 256 + threadIdx.x;
    const int k = i4 >> 6;
    const float4 w = ((const float4*)ema_w)[i4];
    const float4 d = ((const float4*)dw)[i4];
    float4 nw;
    nw.x = fmaf(w.x, 0.99f, 0.01f * d.x);
    nw.y = fmaf(w.y, 0.99f, 0.01f * d.y);
    nw.z = fmaf(w.z, 0.99f, 0.01f * d.z);
    nw.w = fmaf(w.w, 0.99f, 0.01f * d.w);
    ((float4*)out_ema_w)[i4] = nw;
    const float cs = csize[k];
    float4 ne;
    ne.x = nw.x / cs; ne.y = nw.y / cs; ne.z = nw.z / cs; ne.w = nw.w / cs;
    ((float4*)out_emb)[i4] = ne;
    if (i4 == 0) out_loss[0] = 0.25f * loss_acc[0] * (1.0f / (float)NELEM);
}

extern "C" void kernel_launch(void* const* d_in, const int* in_sizes, int n_in,
                              void* d_out, int out_size, void* d_ws, size_t ws_size,
                              hipStream_t stream) {
    const float* z      = (const float*)d_in[0];
    const float* e      = (const float*)d_in[1];
    const float* ema_cs = (const float*)d_in[2];
    const float* ema_w  = (const float*)d_in[3];
    float* out = (float*)d_out;
    float* ws  = (float*)d_ws;

    int*   idx_arr  = (int*)ws;
    int*   flag_cnt = (int*)(ws + 32768);
    int*   counts_i = (int*)(ws + 32769);
    float* loss_acc = ws + 33793;
    int*   flags    = (int*)(ws + 33794);
    float* enorm    = ws + 41986;
    float* csize    = ws + 43010;
    int*   base     = (int*)(ws + 44034);
    int*   offs     = (int*)(ws + 45058);
    int*   order    = (int*)(ws + 46082);
    unsigned short* ebt = (unsigned short*)(ws + 78852);

    unsigned short* zbt = (unsigned short*)out;     // q_out region, written later
    float* dw = out + 8684546;                      // new_emb region (aliased)

    hipMemsetAsync(ws + 32768, 0, 4104, stream);

    vq_eprep<<<dim3(32, 4), 256, 0, stream>>>(e, ebt);
    vq_enorm<<<256, 256, 0, stream>>>(e, enorm);
    vq_zprep<<<dim3(1024, 4), 256, 0, stream>>>(z, zbt);
    vq_argmin_mfma<<<256, 512, 0, stream>>>(zbt, ebt, enorm, idx_arr, counts_i,
                                            flag_cnt, flags);
    vq_fix<<<64, 256, 0, stream>>>(z, e, enorm, flag_cnt, flags, idx_arr, counts_i);
    vq_scan_small<<<1, 1024, 0, stream>>>(counts_i, ema_cs,
                                          out + 8388609, out + 8421378, csize, base, offs);
    vq_scatter<<<128, 256, 0, stream>>>(idx_arr, offs, order);
    vq_dw<<<1024, 256, 0, stream>>>(zbt, order, base, counts_i, dw);
    vq_combine<<<dim3(128, 4), 256, 0, stream>>>(z, e, idx_arr, loss_acc,
                                                 out, out + 8388610);
    vq_finalize_big<<<256, 256, 0, stream>>>(ema_w, dw, csize, loss_acc,
                                             out + 8422402, out + 8684546,
                                             out + 8388608);
}

// Round 5
// 390.602 us; speedup vs baseline: 1.7866x; 1.0641x over previous
//
#include <hip/hip_runtime.h>

#define C_DIM   256
#define HWN     1024
#define N_TOT   32768
#define NELEM   8388608
#define CHW     (C_DIM*HWN)
#define BIGF    3.4e38f
#define FLAG_CAP 8192
#define MARGIN  0.02f

typedef __attribute__((ext_vector_type(8)))  short bf16x8;
typedef __attribute__((ext_vector_type(16))) float f32x16;

// ---------------- ws layout (floats) ----------------
// idx_arr(int): [0, 32768)
// flag_cnt    : 32768 ; counts_i [32769,33793) ; loss_acc 33793   (memset 4104 B)
// flags(int)  : [33794, 41986)
// enorm       : [41986, 43010)
// csize       : [43010, 44034)
// base(int)   : [44034, 45058)
// offs(int)   : [45058, 46082)
// order(int)  : [46082, 78850)
// ebt(bf16)   : [78852, 340996)     -- 1 MB, fragment-ordered hi/lo codebook
//
// zbt (33.5 MB, fragment-ordered hi/lo z) lives in d_out q_out region
// (q written later by vq_combine). dw lives in d_out new_emb region.

__device__ inline unsigned short bf16_rne(float x) {
    unsigned int u = __float_as_uint(x);
    unsigned int r = (u + 0x7FFF + ((u >> 16) & 1)) >> 16;
    return (unsigned short)r;
}
__device__ inline float bf16_to_f(unsigned short h) {
    return __uint_as_float(((unsigned int)h) << 16);
}

// ---------- codebook prep: e -> fragment-ordered bf16 hi/lo planes ----------
__global__ __launch_bounds__(256)
void vq_eprep(const float* __restrict__ e, unsigned short* __restrict__ ebt) {
    const int t = threadIdx.x;
    const int ct = blockIdx.x;          // 0..31
    const int cg = blockIdx.y;          // 0..3
    const int u = t >> 5;
    const int row = t & 31;
    const float* src = e + (size_t)(ct*32 + row)*C_DIM + cg*64 + u*8;
    const float4 v0 = *(const float4*)(src);
    const float4 v1 = *(const float4*)(src + 4);
    const float xs[8] = {v0.x,v0.y,v0.z,v0.w,v1.x,v1.y,v1.z,v1.w};
    __align__(16) unsigned short hi[8], lo[8];
    #pragma unroll
    for (int j = 0; j < 8; j++) {
        hi[j] = bf16_rne(xs[j]);
        lo[j] = bf16_rne(xs[j] - bf16_to_f(hi[j]));
    }
    const int cs = cg*4 + (u >> 1);
    const int lpos = (u & 1)*32 + row;
    unsigned short* dhi = ebt + ((size_t)(ct*2 + 0)*16 + cs)*512 + lpos*8;
    unsigned short* dlo = ebt + ((size_t)(ct*2 + 1)*16 + cs)*512 + lpos*8;
    *(uint4*)dhi = *(const uint4*)hi;
    *(uint4*)dlo = *(const uint4*)lo;
}

__global__ void vq_enorm(const float* __restrict__ e, float* __restrict__ enorm) {
    const int t = threadIdx.x;
    const int w = t >> 6;
    const int lane = t & 63;
    const int k = blockIdx.x * 4 + w;
    const float4 v = *(const float4*)(e + (size_t)k * C_DIM + lane * 4);
    float s = fmaf(v.x, v.x, fmaf(v.y, v.y, fmaf(v.z, v.z, v.w * v.w)));
    #pragma unroll
    for (int off = 32; off > 0; off >>= 1) s += __shfl_down(s, off, 64);
    if (lane == 0) enorm[k] = s;
}

// ---------- z prep ----------
__global__ __launch_bounds__(256)
void vq_zprep(const float* __restrict__ z, unsigned short* __restrict__ zbt) {
    const int t = threadIdx.x;
    const int rt = blockIdx.x;
    const int cg = blockIdx.y;
    const int u = t >> 5;
    const int row = t & 31;
    const int n = rt*32 + row;
    const int b = n >> 10, p = n & 1023;
    const float* zb = z + (size_t)b*CHW + p;
    const int c0 = cg*64 + u*8;
    float xs[8];
    #pragma unroll
    for (int j = 0; j < 8; j++) xs[j] = zb[(size_t)(c0 + j)*HWN];
    __align__(16) unsigned short hi[8], lo[8];
    #pragma unroll
    for (int j = 0; j < 8; j++) {
        hi[j] = bf16_rne(xs[j]);
        lo[j] = bf16_rne(xs[j] - bf16_to_f(hi[j]));
    }
    const int cs = cg*4 + (u >> 1);
    const int lpos = (u & 1)*32 + row;
    unsigned short* base = zbt + (size_t)rt*16384;
    *(uint4*)(base + (0*16 + cs)*512 + lpos*8) = *(const uint4*)hi;
    *(uint4*)(base + (16   + cs)*512 + lpos*8) = *(const uint4*)lo;
}

// ---------- MFMA argmin v2: 256 thr / 64 rows / grid 512 (2 blocks/CU) ----------
// wave w: rg=w>>1 (rows rg*32), cg=w&1 (cols kc*64+cg*32).
// 3-term split: z.e ~= zh.eh + zh.el + zl.eh  (lo*lo dropped, err ~1e-3 << MARGIN)
__global__ __launch_bounds__(256, 2)
void vq_argmin_mfma(const unsigned short* __restrict__ zbt,
                    const unsigned short* __restrict__ ebt,
                    const float* __restrict__ enorm,
                    int* __restrict__ idx_arr, int* __restrict__ counts_i,
                    int* __restrict__ flag_cnt, int* __restrict__ flags) {
    __shared__ __align__(16) unsigned short eslab[16384];   // 32 KB
    __shared__ float redd[64][2];
    __shared__ float reds[64][2];
    __shared__ int   redi[64][2];

    const int t = threadIdx.x;
    const int lane = t & 63;
    const int w = t >> 6;
    const int rg = w >> 1;
    const int cg = w & 1;
    const int col = lane & 31;
    const int h = lane >> 5;
    const int n0 = blockIdx.x * 64;
    const int rt = (n0 >> 5) + rg;

    // A fragments: 32 rows x 256 c, hi+lo (128 VGPR), resident for whole kernel
    bf16x8 Ahi[16], Alo[16];
    const unsigned short* abase = zbt + (size_t)rt * 16384;
    #pragma unroll
    for (int cs = 0; cs < 16; cs++) {
        Ahi[cs] = *(const bf16x8*)(abase + (0*16 + cs)*512 + lane*8);
        Alo[cs] = *(const bf16x8*)(abase + (16   + cs)*512 + lane*8);
    }

    float bestd[16], secondd[16];
    int   besti[16];
    #pragma unroll
    for (int r = 0; r < 16; r++) { bestd[r] = BIGF; secondd[r] = BIGF; besti[r] = 0x7fffffff; }

    const int piece = t >> 6;          // (lt = piece>>1, plane = piece&1)
    const int tl = t & 63;

    for (int kc = 0; kc < 16; kc++) {
        f32x16 acc = {0,0,0,0,0,0,0,0,0,0,0,0,0,0,0,0};
        #pragma unroll
        for (int ph = 0; ph < 2; ph++) {
            __syncthreads();
            {   // stage 32 KB: 64 threads per piece, 8 x 1KB rows each
                const int lt = piece >> 1, pl = piece & 1;
                const int ct = kc*2 + lt;
                const unsigned short* src = ebt + ((size_t)(ct*2 + pl)*16 + ph*8)*512 + tl*8;
                unsigned short* dst = eslab + (size_t)piece*4096 + tl*8;
                #pragma unroll
                for (int r = 0; r < 8; r++)
                    *(uint4*)(dst + r*512) = *(const uint4*)(src + r*512);
            }
            __syncthreads();
            #pragma unroll
            for (int csl = 0; csl < 8; csl++) {
                const int cs = ph*8 + csl;
                const bf16x8 bh = *(const bf16x8*)(eslab + ((cg*2 + 0)*8 + csl)*512 + lane*8);
                const bf16x8 bl = *(const bf16x8*)(eslab + ((cg*2 + 1)*8 + csl)*512 + lane*8);
                acc = __builtin_amdgcn_mfma_f32_32x32x16_bf16(Ahi[cs], bh, acc, 0, 0, 0);
                acc = __builtin_amdgcn_mfma_f32_32x32x16_bf16(Ahi[cs], bl, acc, 0, 0, 0);
                acc = __builtin_amdgcn_mfma_f32_32x32x16_bf16(Alo[cs], bh, acc, 0, 0, 0);
            }
        }
        const int code = kc*64 + cg*32 + col;
        const float en = enorm[code];
        #pragma unroll
        for (int r = 0; r < 16; r++) {
            const float d = fmaf(-2.0f, acc[r], en);
            if (d < bestd[r]) { secondd[r] = bestd[r]; bestd[r] = d; besti[r] = code; }
            else if (d < secondd[r]) secondd[r] = d;
        }
    }

    #pragma unroll
    for (int m = 1; m < 32; m <<= 1) {
        #pragma unroll
        for (int r = 0; r < 16; r++) {
            const float od = __shfl_xor(bestd[r],   m, 64);
            const int   oi = __shfl_xor(besti[r],   m, 64);
            const float os = __shfl_xor(secondd[r], m, 64);
            const bool take = (od < bestd[r]) || (od == bestd[r] && oi < besti[r]);
            const float ns = take ? fminf(bestd[r], os) : fminf(secondd[r], od);
            if (take) { bestd[r] = od; besti[r] = oi; }
            secondd[r] = ns;
        }
    }
    __syncthreads();
    if (col == 0) {
        #pragma unroll
        for (int r = 0; r < 16; r++) {
            const int row = (r & 3) + 8*(r >> 2) + 4*h;
            redd[rg*32 + row][cg] = bestd[r];
            redi[rg*32 + row][cg] = besti[r];
            reds[rg*32 + row][cg] = secondd[r];
        }
    }
    __syncthreads();
    if (t < 64) {
        const float d0 = redd[t][0], d1 = redd[t][1];
        const int   i0 = redi[t][0], i1 = redi[t][1];
        const float s0 = reds[t][0], s1 = reds[t][1];
        const bool take = (d1 < d0) || (d1 == d0 && i1 < i0);
        const float bd = take ? d1 : d0;
        const int   bi = take ? i1 : i0;
        const float sd = take ? fminf(d0, s1) : fminf(s0, d1);
        const int n = n0 + t;
        idx_arr[n] = bi;
        atomicAdd(&counts_i[bi], 1);
        if (sd - bd < MARGIN) {
            const int pos = atomicAdd(flag_cnt, 1);
            if (pos < FLAG_CAP) flags[pos] = n;
        }
    }
}

// ---------- exact fp32 re-argmin for near-tie points (fixes counts too) ----------
__global__ __launch_bounds__(256)
void vq_fix(const float* __restrict__ z, const float* __restrict__ e,
            const float* __restrict__ enorm,
            const int* __restrict__ flag_cnt, const int* __restrict__ flags,
            int* __restrict__ idx_arr, int* __restrict__ counts_i) {
    __shared__ float zrow[256];
    __shared__ float rd[256];
    __shared__ int   ri[256];
    const int t = threadIdx.x;
    int cnt = *flag_cnt;
    if (cnt > FLAG_CAP) cnt = FLAG_CAP;
    for (int fi = blockIdx.x; fi < cnt; fi += (int)gridDim.x) {
        const int n = flags[fi];
        const int b = n >> 10, p = n & 1023;
        __syncthreads();
        zrow[t] = z[(size_t)b*CHW + (size_t)t*HWN + p];
        __syncthreads();
        float bd = BIGF; int bi = 0;
        for (int q = 0; q < 4; q++) {
            const int k = t*4 + q;
            const float* er = e + (size_t)k*C_DIM;
            float acc = 0.0f;
            for (int c = 0; c < C_DIM; c += 4) {
                const float4 ev = *(const float4*)(er + c);
                acc = fmaf(ev.x, zrow[c],   acc);
                acc = fmaf(ev.y, zrow[c+1], acc);
                acc = fmaf(ev.z, zrow[c+2], acc);
                acc = fmaf(ev.w, zrow[c+3], acc);
            }
            const float d = fmaf(-2.0f, acc, enorm[k]);
            if (d < bd) { bd = d; bi = k; }
        }
        rd[t] = bd; ri[t] = bi;
        __syncthreads();
        for (int s = 128; s > 0; s >>= 1) {
            if (t < s) {
                const float d2 = rd[t+s]; const int i2 = ri[t+s];
                if (d2 < rd[t] || (d2 == rd[t] && i2 < ri[t])) { rd[t] = d2; ri[t] = i2; }
            }
            __syncthreads();
        }
        if (t == 0) {
            const int old = idx_arr[n];
            if (ri[0] != old) {
                idx_arr[n] = ri[0];
                atomicAdd(&counts_i[old], -1);
                atomicAdd(&counts_i[ri[0]], 1);
            }
        }
        __syncthreads();
    }
}

// 1 block, 1024 threads: EMA cluster size, csize, perplexity, prefix scan.
__global__ void vq_scan_small(const int* __restrict__ counts_i,
                              const float* __restrict__ ema_cs,
                              float* __restrict__ out_perp,
                              float* __restrict__ out_ncs,
                              float* __restrict__ csize,
                              int* __restrict__ base, int* __restrict__ offs) {
    __shared__ float sf[1024];
    __shared__ int si[1024];
    const int t = threadIdx.x;
    const int ci = counts_i[t];
    const float cnt = (float)ci;
    const float ncs = ema_cs[t] * 0.99f + 0.01f * cnt;
    out_ncs[t] = ncs;

    sf[t] = ncs;
    __syncthreads();
    for (int s = 512; s > 0; s >>= 1) { if (t < s) sf[t] += sf[t + s]; __syncthreads(); }
    const float n_total = sf[0];
    __syncthreads();

    csize[t] = (ncs + 1e-10f) / (n_total + 1024.0f * 1e-10f) * n_total;

    const float pr = cnt * (1.0f / 32768.0f);
    sf[t] = pr * logf(pr + 1e-10f);
    __syncthreads();
    for (int s = 512; s > 0; s >>= 1) { if (t < s) sf[t] += sf[t + s]; __syncthreads(); }
    if (t == 0) out_perp[0] = expf(-sf[0]);

    si[t] = ci;
    __syncthreads();
    for (int d = 1; d < 1024; d <<= 1) {
        const int x = si[t];
        const int y = (t >= d) ? si[t - d] : 0;
        __syncthreads();
        si[t] = x + y;
        __syncthreads();
    }
    const int excl = si[t] - ci;
    base[t] = excl;
    offs[t] = excl;
}

__global__ __launch_bounds__(256)
void vq_scatter(const int* __restrict__ idx_arr, int* __restrict__ offs,
                int* __restrict__ order) {
    const int n = blockIdx.x * 256 + threadIdx.x;
    const int idx = idx_arr[n];
    const int pos = atomicAdd(&offs[idx], 1);
    order[pos] = n;
}

// ---------- dw: wave-per-point coalesced reads, unroll-8, LDS reduce ----------
__global__ __launch_bounds__(256)
void vq_dw(const unsigned short* __restrict__ zbt, const int* __restrict__ order,
           const int* __restrict__ base, const int* __restrict__ counts_i,
           float* __restrict__ dw) {
    __shared__ int sord[1024];
    __shared__ float red[4][256];
    const int k = blockIdx.x;
    const int t = threadIdx.x;
    const int w = t >> 6;
    const int l = t & 63;
    const int plane = l >> 5;
    const int cs = (l >> 1) & 15;
    const int hh = l & 1;
    const int start = base[k];
    const int cnt = counts_i[k];
    const size_t loff = (size_t)(plane*16 + cs)*512 + hh*256;

    float acc[8] = {0,0,0,0,0,0,0,0};

    for (int s0 = 0; s0 < cnt; s0 += 1024) {
        const int m = min(1024, cnt - s0);
        __syncthreads();
        for (int i = t; i < m; i += 256) sord[i] = order[start + s0 + i];
        __syncthreads();
        const int mm = m & ~31;
        for (int g0 = w*8; g0 < mm; g0 += 32) {
            uint4 v[8];
            #pragma unroll
            for (int r = 0; r < 8; r++) {
                const int n = sord[g0 + r];
                const int rt = n >> 5, row = n & 31;
                v[r] = *(const uint4*)(zbt + (size_t)rt*16384 + loff + row*8);
            }
            #pragma unroll
            for (int r = 0; r < 8; r++) {
                const unsigned short* u = (const unsigned short*)&v[r];
                #pragma unroll
                for (int j = 0; j < 8; j++) acc[j] += bf16_to_f(u[j]);
            }
        }
        for (int i = mm + w; i < m; i += 4) {
            const int n = sord[i];
            const int rt = n >> 5, row = n & 31;
            const uint4 v = *(const uint4*)(zbt + (size_t)rt*16384 + loff + row*8);
            const unsigned short* u = (const unsigned short*)&v;
            #pragma unroll
            for (int j = 0; j < 8; j++) acc[j] += bf16_to_f(u[j]);
        }
    }

    #pragma unroll
    for (int j = 0; j < 8; j++) acc[j] += __shfl_xor(acc[j], 32, 64);
    if (l < 32) {
        #pragma unroll
        for (int j = 0; j < 8; j++) red[w][cs*16 + hh*8 + j] = acc[j];
    }
    __syncthreads();
    dw[(size_t)k*C_DIM + t] = red[0][t] + red[1][t] + red[2][t] + red[3][t];
}

// q_out, token_map, loss. Runs AFTER vq_dw (overwrites zbt region with q).
__global__ __launch_bounds__(256)
void vq_combine(const float* __restrict__ z, const float* __restrict__ e,
                const int* __restrict__ idx_arr,
                float* __restrict__ loss_acc,
                float* __restrict__ qout, float* __restrict__ tokmap) {
    const int t = threadIdx.x;
    const int n = blockIdx.x * 256 + t;
    const int csplit = blockIdx.y;
    const int b = n >> 10, p = n & 1023;
    const int idx = idx_arr[n];
    if (csplit == 0) tokmap[n] = (float)idx;

    const float* zrow = z + (size_t)b*CHW + p;
    float* qrow = qout + (size_t)b*CHW + p;
    const float* erow = e + (size_t)idx*C_DIM;

    float lsum = 0.0f;
    for (int cc = 0; cc < 64; cc += 16) {
        const int cb = csplit*64 + cc;
        float ev[16];
        #pragma unroll
        for (int q4 = 0; q4 < 4; q4++) {
            const float4 v = *(const float4*)(erow + cb + q4*4);
            ev[q4*4+0] = v.x; ev[q4*4+1] = v.y; ev[q4*4+2] = v.z; ev[q4*4+3] = v.w;
        }
        #pragma unroll
        for (int j = 0; j < 16; j++) {
            const float zv = zrow[(size_t)(cb + j) * HWN];
            qrow[(size_t)(cb + j) * HWN] = ev[j];
            const float df = ev[j] - zv;
            lsum = fmaf(df, df, lsum);
        }
    }
    #pragma unroll
    for (int off = 32; off > 0; off >>= 1) lsum += __shfl_down(lsum, off, 64);
    __shared__ float ls[4];
    if ((t & 63) == 0) ls[t >> 6] = lsum;
    __syncthreads();
    if (t == 0) atomicAdd(loss_acc, ls[0] + ls[1] + ls[2] + ls[3]);
}

__global__ __launch_bounds__(256)
void vq_finalize_big(const float* __restrict__ ema_w, const float* __restrict__ dw,
                     const float* __restrict__ csize, const float* __restrict__ loss_acc,
                     float* __restrict__ out_ema_w, float* __restrict__ out_emb,
                     float* __restrict__ out_loss) {
    const int i4 = blockIdx.x * 256 + threadIdx.x;
    const int k = i4 >> 6;
    const float4 w = ((const float4*)ema_w)[i4];
    const float4 d = ((const float4*)dw)[i4];
    float4 nw;
    nw.x = fmaf(w.x, 0.99f, 0.01f * d.x);
    nw.y = fmaf(w.y, 0.99f, 0.01f * d.y);
    nw.z = fmaf(w.z, 0.99f, 0.01f * d.z);
    nw.w = fmaf(w.w, 0.99f, 0.01f * d.w);
    ((float4*)out_ema_w)[i4] = nw;
    const float cs = csize[k];
    float4 ne;
    ne.x = nw.x / cs; ne.y = nw.y / cs; ne.z = nw.z / cs; ne.w = nw.w / cs;
    ((float4*)out_emb)[i4] = ne;
    if (i4 == 0) out_loss[0] = 0.25f * loss_acc[0] * (1.0f / (float)NELEM);
}

extern "C" void kernel_launch(void* const* d_in, const int* in_sizes, int n_in,
                              void* d_out, int out_size, void* d_ws, size_t ws_size,
                              hipStream_t stream) {
    const float* z      = (const float*)d_in[0];
    const float* e      = (const float*)d_in[1];
    const float* ema_cs = (const float*)d_in[2];
    const float* ema_w  = (const float*)d_in[3];
    float* out = (float*)d_out;
    float* ws  = (float*)d_ws;

    int*   idx_arr  = (int*)ws;
    int*   flag_cnt = (int*)(ws + 32768);
    int*   counts_i = (int*)(ws + 32769);
    float* loss_acc = ws + 33793;
    int*   flags    = (int*)(ws + 33794);
    float* enorm    = ws + 41986;
    float* csize    = ws + 43010;
    int*   base     = (int*)(ws + 44034);
    int*   offs     = (int*)(ws + 45058);
    int*   order    = (int*)(ws + 46082);
    unsigned short* ebt = (unsigned short*)(ws + 78852);

    unsigned short* zbt = (unsigned short*)out;     // q_out region, written later
    float* dw = out + 8684546;                      // new_emb region (aliased)

    hipMemsetAsync(ws + 32768, 0, 4104, stream);

    vq_eprep<<<dim3(32, 4), 256, 0, stream>>>(e, ebt);
    vq_enorm<<<256, 256, 0, stream>>>(e, enorm);
    vq_zprep<<<dim3(1024, 4), 256, 0, stream>>>(z, zbt);
    vq_argmin_mfma<<<512, 256, 0, stream>>>(zbt, ebt, enorm, idx_arr, counts_i,
                                            flag_cnt, flags);
    vq_fix<<<64, 256, 0, stream>>>(z, e, enorm, flag_cnt, flags, idx_arr, counts_i);
    vq_scan_small<<<1, 1024, 0, stream>>>(counts_i, ema_cs,
                                          out + 8388609, out + 8421378, csize, base, offs);
    vq_scatter<<<128, 256, 0, stream>>>(idx_arr, offs, order);
    vq_dw<<<1024, 256, 0, stream>>>(zbt, order, base, counts_i, dw);
    vq_combine<<<dim3(128, 4), 256, 0, stream>>>(z, e, idx_arr, loss_acc,
                                                 out, out + 8388610);
    vq_finalize_big<<<256, 256, 0, stream>>>(ema_w, dw, csize, loss_acc,
                                             out + 8422402, out + 8684546,
                                             out + 8388608);
}